// Round 9
// baseline (241.174 us; speedup 1.0000x reference)
//
#include <hip/hip_runtime.h>
#include <hip/hip_bf16.h>

// TDNN as GEMM: out[m,o] = relu(bias[o] + sum_kk A[m,kk]*W[kk,o])
//   A[m,kk] = x[b, t+kw, c] (contiguous 2560-elem slice of fp32 x)
// R9: R6's proven loop (128x128 tile, 4 waves, B fragment-native in regs from
// L2, counted vmcnt + 1 barrier/K-tile, 0-conflict XOR swizzle, 4-buf A LDS
// rotation) with the fp32->bf16 conversion FUSED into A-staging:
// reg-stage (8x dwordx4 fp32 at tile top) -> cvt -> 4x ds_write_b128 at tile
// end (T14 split). Eliminates the cvt_x pre-pass (~22 us incl. launch).

#define BATCH 64
#define SEQ   1000
#define CIN   512
#define COUT  512
#define TOUT  996
#define KTOT  2560
#define MTOT  63744
#define NKT   40            // K-tiles of 64
#define MT    498           // MTOT/128
#define NT    4             // COUT/128
#define NWG   (MT*NT)       // 1992 = 8*249

typedef __bf16 bf16x8 __attribute__((ext_vector_type(8)));
typedef float  f32x4  __attribute__((ext_vector_type(4)));

#define BAR()    __builtin_amdgcn_s_barrier()
#define VM8()    asm volatile("s_waitcnt vmcnt(8)"  ::: "memory")
#define VM0()    asm volatile("s_waitcnt vmcnt(0)"  ::: "memory")
#define LGKM0()  asm volatile("s_waitcnt lgkmcnt(0)" ::: "memory")
#define PRIO(x)  __builtin_amdgcn_s_setprio(x)
#define SCHED0() __builtin_amdgcn_sched_barrier(0)
#define MFMA(d, x, y) d = __builtin_amdgcn_mfma_f32_16x16x32_bf16(x, y, d, 0, 0, 0)

// ---- kernel [O][C][KW] fp32 -> Wt2 fragment-native bf16 ----
// elem idx = ((ks*32 + ob)*64 + l)*8 + j
//   col o = ob*16 + (l&15); k = ks*32 + ((l>>4)&3)*8 + j; c = k&511; kw = k>>9
__global__ void cvt_w_kernel(const float* __restrict__ k, __bf16* __restrict__ wt) {
  int idx = blockIdx.x * blockDim.x + threadIdx.x;   // 1,310,720
  if (idx >= 80 * 32 * 512) return;
  int j  = idx & 7;
  int l  = (idx >> 3) & 63;
  int t1 = idx >> 9;
  int ob = t1 & 31;
  int ks = t1 >> 5;
  int o  = ob * 16 + (l & 15);
  int kk = ks * 32 + ((l >> 4) & 3) * 8 + j;
  int c  = kk & 511, kw = kk >> 9;
  wt[idx] = (__bf16)k[(o * CIN + c) * 5 + kw];
}

// issue A-stage loads for K-tile kt: 4 segments x 8 fp32 (2x dwordx4 each)
#define LOADA(kt) do { \
    const float* p_; \
    p_ = Xf + offA0 + (kt) * 64; fa00 = *(const f32x4*)p_; fa01 = *(const f32x4*)(p_ + 4); \
    p_ = Xf + offA1 + (kt) * 64; fa10 = *(const f32x4*)p_; fa11 = *(const f32x4*)(p_ + 4); \
    p_ = Xf + offA2 + (kt) * 64; fa20 = *(const f32x4*)p_; fa21 = *(const f32x4*)(p_ + 4); \
    p_ = Xf + offA3 + (kt) * 64; fa30 = *(const f32x4*)p_; fa31 = *(const f32x4*)(p_ + 4); } while (0)

// convert staged fp32 -> bf16 and ds_write_b128 into LDS buffer `buf`
#define CVW1(lo, hi, dof, buf) do { \
    bf16x8 v_; \
    v_[0] = (__bf16)lo[0]; v_[1] = (__bf16)lo[1]; v_[2] = (__bf16)lo[2]; v_[3] = (__bf16)lo[3]; \
    v_[4] = (__bf16)hi[0]; v_[5] = (__bf16)hi[1]; v_[6] = (__bf16)hi[2]; v_[7] = (__bf16)hi[3]; \
    *(bf16x8*)((char*)Ab + ((buf) << 14) + dof) = v_; } while (0)
#define WRITEA(buf) do { \
    CVW1(fa00, fa01, dof0, buf); \
    CVW1(fa10, fa11, dof1, buf); \
    CVW1(fa20, fa21, dof2, buf); \
    CVW1(fa30, fa31, dof3, buf); } while (0)

// load next-tile B fragments from global (L2-resident), 8 x dwordx4
#define LOADB(bn, Tn) do { \
    const char* p_ = Wglob + (size_t)(Tn) * 65536; \
    bn[0][0] = *(const bf16x8*)(p_ +     0); bn[0][1] = *(const bf16x8*)(p_ + 32768); \
    bn[1][0] = *(const bf16x8*)(p_ +  1024); bn[1][1] = *(const bf16x8*)(p_ + 33792); \
    bn[2][0] = *(const bf16x8*)(p_ +  2048); bn[2][1] = *(const bf16x8*)(p_ + 34816); \
    bn[3][0] = *(const bf16x8*)(p_ +  3072); bn[3][1] = *(const bf16x8*)(p_ + 35840); } while (0)

// one K-tile: issue A(T+2) fp32 loads, B(T+1) frag loads; 8 ds_read + 32 MFMA;
// VM8 drains A (leaves B(T+1) in flight); cvt+ds_write A(T+2); barrier.
#define TILE(T, bc, bn) do { \
    const bool s1_ = (T) + 1 < NKT, s2_ = (T) + 2 < NKT; \
    if (s2_) LOADA((T) + 2); \
    if (s1_) LOADB(bn, (T) + 1); \
    const char* Ac_ = Aw + (((T) & 3) << 14); \
    bf16x8 a_[4][2]; \
    _Pragma("unroll") \
    for (int mi = 0; mi < 4; ++mi) { \
      a_[mi][0] = *(const bf16x8*)(Ac_ + mi * 2048 + off0); \
      a_[mi][1] = *(const bf16x8*)(Ac_ + mi * 2048 + off1); \
    } \
    PRIO(1); \
    _Pragma("unroll") \
    for (int mi = 0; mi < 4; ++mi) \
      _Pragma("unroll") \
      for (int nj = 0; nj < 4; ++nj) { \
        MFMA(acc[mi][nj], a_[mi][0], bc[nj][0]); \
        MFMA(acc[mi][nj], a_[mi][1], bc[nj][1]); \
      } \
    PRIO(0); \
    SCHED0(); \
    if (s2_) { VM8(); WRITEA(((T) + 2) & 3); } \
    if (s1_) BAR(); \
  } while (0)

__global__ __launch_bounds__(256, 2)
void tdnn_gemm_kernel(const float* __restrict__ Xf, const __bf16* __restrict__ Wt2,
                      const float* __restrict__ bias, float* __restrict__ out) {
  // A only: 4 rotating K-tile buffers x 128 rows x 64 bf16 = 64 KiB
  __shared__ __bf16 Ab[4][128][64];

  const int tid  = threadIdx.x;
  const int wave = tid >> 6;
  const int lane = tid & 63;
  const int wr = wave >> 1;          // 0..1 : 64-row band
  const int wc = wave & 1;           // 0..1 : 64-col band

  // bijective XCD swizzle: 1992 = 8*249; consecutive swz share the A-panel
  int bid = blockIdx.x;
  int swz = (bid & 7) * 249 + (bid >> 3);
  const int m0 = (swz >> 2) * 128;
  const int n0 = (swz & 3) * 128;

  // ---- A staging offsets (pre-swizzled global source, linear LDS dest)
  int offA0, offA1, offA2, offA3, dof0, dof1, dof2, dof3;
  {
    int rr, ce, m, b, tt;
#define MKOFF(l, A, D) \
    rr = (l) * 32 + (tid >> 3); \
    ce = (((tid & 7) ^ (rr & 7)) << 3); \
    D  = ((l) * 256 + tid) * 16; \
    m = m0 + rr; b = m / TOUT; tt = m - b * TOUT; \
    A = (b * SEQ + tt) * CIN + ce;
    MKOFF(0, offA0, dof0)
    MKOFF(1, offA1, dof1)
    MKOFF(2, offA2, dof2)
    MKOFF(3, offA3, dof3)
#undef MKOFF
  }

  // ---- fragment read geometry (A from LDS, T2 read-side XOR)
  const int frow = lane & 15;
  const int fkb  = (lane >> 4) << 4;        // 0,16,32,48 bytes
  const int xorv = (frow & 7) << 4;
  const int off0 = fkb ^ xorv;              // k-slice 0
  const int off1 = (64 + fkb) ^ xorv;       // k-slice 1
  const char* Aw = (const char*)Ab + (wr * 64 + frow) * 128;

  // ---- B fragment-native global base for this wave
  const int obW = (n0 >> 4) + wc * 4;
  const char* Wglob = (const char*)Wt2 + obW * 1024 + lane * 16;

  f32x4 acc[4][4];
  const f32x4 z = {0.f, 0.f, 0.f, 0.f};
#pragma unroll
  for (int i = 0; i < 4; i++)
#pragma unroll
    for (int j = 0; j < 4; j++) acc[i][j] = z;

  bf16x8 bA[4][2], bB[4][2];
  f32x4 fa00, fa01, fa10, fa11, fa20, fa21, fa30, fa31;

  // ---- prologue: stage tiles 0,1 (load->cvt->write), B(0)->bA
  LOADA(0);
  LOADB(bA, 0);
  VM8();            // drain A(0) (oldest 8); B(0) may remain in flight
  WRITEA(0);
  LOADA(1);
  VM0();            // prologue-only full drain (B(0) + A(1))
  WRITEA(1);
  LGKM0();          // ds_writes visible before first reads
  BAR();

  for (int T = 0; T < NKT; T += 2) {
    TILE(T,     bA, bB);
    TILE(T + 1, bB, bA);
  }

  // ---- epilogue: bias + relu + store. C/D map: col=lane&15, row=(lane>>4)*4+reg
  const int ccol = lane & 15;
  const int crow = (lane >> 4) * 4;
  float bv[4];
#pragma unroll
  for (int nj = 0; nj < 4; ++nj)
    bv[nj] = bias[n0 + wc * 64 + nj * 16 + ccol];

#pragma unroll
  for (int mi = 0; mi < 4; ++mi) {
    const int mrow = m0 + wr * 64 + mi * 16 + crow;
#pragma unroll
    for (int nj = 0; nj < 4; ++nj) {
      const int ocol = n0 + wc * 64 + nj * 16 + ccol;
#pragma unroll
      for (int j = 0; j < 4; ++j) {
        float v = acc[mi][nj][j] + bv[nj];
        v = v > 0.f ? v : 0.f;
        out[(size_t)(mrow + j) * COUT + ocol] = v;
      }
    }
  }
}

extern "C" void kernel_launch(void* const* d_in, const int* in_sizes, int n_in,
                              void* d_out, int out_size, void* d_ws, size_t ws_size,
                              hipStream_t stream) {
  const float* x      = (const float*)d_in[0];   // [64,1000,512] fp32
  const float* kernel = (const float*)d_in[1];   // [512,512,5]   fp32
  const float* bias   = (const float*)d_in[2];   // [512]         fp32
  float* out          = (float*)d_out;           // [64,996,512]  fp32

  __bf16* wt2 = (__bf16*)d_ws;                   // 2,621,440 B

  cvt_w_kernel<<<(80 * 32 * 512 + 255) / 256, 256, 0, stream>>>(kernel, wt2);
  tdnn_gemm_kernel<<<NWG, 256, 0, stream>>>(x, wt2, bias, out);
}

// Round 10
// 202.490 us; speedup vs baseline: 1.1910x; 1.1910x over previous
//
#include <hip/hip_runtime.h>
#include <hip/hip_bf16.h>

// TDNN as GEMM: out[m,o] = relu(bias[o] + sum_kk A[m,kk]*W[kk,o])
//   A[m,kk] = x[b, t+kw, c] (contiguous 2560-elem slice of x)
// R10: lean 128x128 kernel built to fit 3 blocks/CU (m114 cross-block
// MFMA/memory co-scheduling):
//   - A: 3-buffer LDS rotation (48 KiB), gload_lds, 0-conflict XOR swizzle,
//     compile-time buffer indices (period-3 unroll)
//   - B: SINGLE-buffered fragment-native regs from L2 (32 VGPR), reloaded
//     after last use each tile; dep-latency covered by co-resident blocks
//   - a-frags read in 2-mi halves (16 live VGPR)
//   - counted VM12/VM8 + 1 barrier per K-tile
// Register budget: ~88 arch + 64 acc ~= 152/wave -> launch_bounds(256,3) safe.

#define BATCH 64
#define SEQ   1000
#define CIN   512
#define COUT  512
#define TOUT  996
#define KTOT  2560
#define MTOT  63744
#define NKT   40            // K-tiles of 64
#define MT    498           // MTOT/128
#define NT    4             // COUT/128
#define NWG   (MT*NT)       // 1992 = 8*249
#define NX    (BATCH*SEQ*CIN)   // 32,768,000
#define NW    (80*32*512)       // 1,310,720 Wt2 elems

typedef __bf16 bf16x8 __attribute__((ext_vector_type(8)));
typedef float  f32x4  __attribute__((ext_vector_type(4)));

__device__ __forceinline__ void gload_lds16(const void* g, void* l) {
  __builtin_amdgcn_global_load_lds(
      (const __attribute__((address_space(1))) void*)g,
      (__attribute__((address_space(3))) void*)l, 16, 0, 0);
}

#define BAR()    __builtin_amdgcn_s_barrier()
#define VM12()   asm volatile("s_waitcnt vmcnt(12)" ::: "memory")
#define VM8()    asm volatile("s_waitcnt vmcnt(8)"  ::: "memory")
#define VM4()    asm volatile("s_waitcnt vmcnt(4)"  ::: "memory")
#define PRIO(x)  __builtin_amdgcn_s_setprio(x)
#define MFMA(d, x, y) d = __builtin_amdgcn_mfma_f32_16x16x32_bf16(x, y, d, 0, 0, 0)

// ---- fused convert: x fp32 -> xb bf16 (vectorized) + kernel -> Wt2 ----
// Wt2 elem idx = ((ks*32 + ob)*64 + l)*8 + j
//   col o = ob*16 + (l&15); k = ks*32 + ((l>>4)&3)*8 + j; c = k&511; kw = k>>9
__global__ void cvt_kernel(const float* __restrict__ x, __bf16* __restrict__ xb,
                           const float* __restrict__ k, __bf16* __restrict__ wt) {
  int i = blockIdx.x * blockDim.x + threadIdx.x;
  if (i < NX / 8) {
    int e = i * 8;
    float4 f0 = *(const float4*)(x + e);
    float4 f1 = *(const float4*)(x + e + 4);
    bf16x8 v;
    v[0] = (__bf16)f0.x; v[1] = (__bf16)f0.y; v[2] = (__bf16)f0.z; v[3] = (__bf16)f0.w;
    v[4] = (__bf16)f1.x; v[5] = (__bf16)f1.y; v[6] = (__bf16)f1.z; v[7] = (__bf16)f1.w;
    *(bf16x8*)(xb + e) = v;
  } else {
    int idx = i - NX / 8;
    if (idx >= NW) return;
    int j  = idx & 7;
    int l  = (idx >> 3) & 63;
    int t1 = idx >> 9;
    int ob = t1 & 31;
    int ks = t1 >> 5;
    int o  = ob * 16 + (l & 15);
    int kk = ks * 32 + ((l >> 4) & 3) * 8 + j;
    int c  = kk & 511, kw = kk >> 9;
    wt[idx] = (__bf16)k[(o * CIN + c) * 5 + kw];
  }
}

// stage one A K-tile (128 rows x 64 bf16 = 16 KiB) into LDS buffer `buf` (literal)
#define STAGE(buf, kt) do { \
    char* d_ = (char*)Ab + ((buf) << 14); \
    gload_lds16(Xb + offA0 + (kt) * 64, d_ + dof0); \
    gload_lds16(Xb + offA1 + (kt) * 64, d_ + dof1); \
    gload_lds16(Xb + offA2 + (kt) * 64, d_ + dof2); \
    gload_lds16(Xb + offA3 + (kt) * 64, d_ + dof3); } while (0)

// (re)load B fragments for tile Tn from global (L2-resident), 8 x dwordx4
#define LOADB(Tn) do { \
    const char* p_ = Wglob + (size_t)(Tn) * 65536; \
    bc[0][0] = *(const bf16x8*)(p_ +     0); bc[0][1] = *(const bf16x8*)(p_ + 32768); \
    bc[1][0] = *(const bf16x8*)(p_ +  1024); bc[1][1] = *(const bf16x8*)(p_ + 33792); \
    bc[2][0] = *(const bf16x8*)(p_ +  2048); bc[2][1] = *(const bf16x8*)(p_ + 34816); \
    bc[3][0] = *(const bf16x8*)(p_ +  3072); bc[3][1] = *(const bf16x8*)(p_ + 35840); } while (0)

// one K-tile. Queue at VM12: A(T+2)x4 then B(T+1)x8 = 12 newest; drains A(T+1)
// and older. Tail (s2_ false): VM8 drains A(T+1..) leaving only B(T+1).
#define TILE(T, bufc, bufs) do { \
    const bool s1_ = (T) + 1 < NKT, s2_ = (T) + 2 < NKT; \
    if (s2_) STAGE(bufs, (T) + 2); \
    const char* Ac_ = Aw + ((bufc) << 14); \
    _Pragma("unroll") \
    for (int h = 0; h < 2; ++h) { \
      bf16x8 a_[2][2]; \
      _Pragma("unroll") \
      for (int mi = 0; mi < 2; ++mi) { \
        a_[mi][0] = *(const bf16x8*)(Ac_ + (h * 2 + mi) * 2048 + off0); \
        a_[mi][1] = *(const bf16x8*)(Ac_ + (h * 2 + mi) * 2048 + off1); \
      } \
      PRIO(1); \
      _Pragma("unroll") \
      for (int mi = 0; mi < 2; ++mi) \
        _Pragma("unroll") \
        for (int nj = 0; nj < 4; ++nj) { \
          MFMA(acc[h * 2 + mi][nj], a_[mi][0], bc[nj][0]); \
          MFMA(acc[h * 2 + mi][nj], a_[mi][1], bc[nj][1]); \
        } \
      PRIO(0); \
    } \
    if (s1_) LOADB((T) + 1); \
    if (s2_) { VM12(); } else if (s1_) { VM8(); } \
    if (s1_) BAR(); \
  } while (0)

__global__ __launch_bounds__(256, 3)
void tdnn_gemm_kernel(const __bf16* __restrict__ Xb, const __bf16* __restrict__ Wt2,
                      const float* __restrict__ bias, float* __restrict__ out) {
  // A only: 3 rotating K-tile buffers x 128 rows x 64 bf16 = 48 KiB
  __shared__ __bf16 Ab[3][128][64];

  const int tid  = threadIdx.x;
  const int wave = tid >> 6;
  const int lane = tid & 63;
  const int wr = wave >> 1;          // 0..1 : 64-row band
  const int wc = wave & 1;           // 0..1 : 64-col band

  // bijective XCD swizzle: 1992 = 8*249; consecutive swz share the A-panel
  int bid = blockIdx.x;
  int swz = (bid & 7) * 249 + (bid >> 3);
  const int m0 = (swz >> 2) * 128;
  const int n0 = (swz & 3) * 128;

  // ---- A staging offsets (pre-swizzled global source, linear LDS dest)
  int offA0, offA1, offA2, offA3, dof0, dof1, dof2, dof3;
  {
    int rr, ce, m, b, tt;
#define MKOFF(l, A, D) \
    rr = (l) * 32 + (tid >> 3); \
    ce = (((tid & 7) ^ (rr & 7)) << 3); \
    D  = ((l) * 256 + tid) * 16; \
    m = m0 + rr; b = m / TOUT; tt = m - b * TOUT; \
    A = (b * SEQ + tt) * CIN + ce;
    MKOFF(0, offA0, dof0)
    MKOFF(1, offA1, dof1)
    MKOFF(2, offA2, dof2)
    MKOFF(3, offA3, dof3)
#undef MKOFF
  }

  // ---- fragment read geometry (A from LDS, T2 read-side XOR)
  const int frow = lane & 15;
  const int fkb  = (lane >> 4) << 4;        // 0,16,32,48 bytes
  const int xorv = (frow & 7) << 4;
  const int off0 = fkb ^ xorv;              // k-slice 0
  const int off1 = (64 + fkb) ^ xorv;       // k-slice 1
  const char* Aw = (const char*)Ab + (wr * 64 + frow) * 128;

  // ---- B fragment-native global base for this wave
  const int obW = (n0 >> 4) + wc * 4;
  const char* Wglob = (const char*)Wt2 + obW * 1024 + lane * 16;

  f32x4 acc[4][4];
  const f32x4 z = {0.f, 0.f, 0.f, 0.f};
#pragma unroll
  for (int i = 0; i < 4; i++)
#pragma unroll
    for (int j = 0; j < 4; j++) acc[i][j] = z;

  bf16x8 bc[4][2];

  // ---- prologue: queue = A(0)x4, B(0)x8, A(1)x4; VM4 drains A(0)+B(0)
  // (B consumed via reg-dep anyway), leaves A(1) in flight.
  STAGE(0, 0);
  LOADB(0);
  STAGE(1, 1);
  VM4();
  BAR();

  // tile T uses buffer T%3; stages (T+2)%3. Period-3 literal unroll.
  for (int T = 0; T < 39; T += 3) {
    TILE(T,     0, 2);
    TILE(T + 1, 1, 0);
    TILE(T + 2, 2, 1);
  }
  TILE(39, 0, 1);   // tail: no stage/loadb/barrier (s1_,s2_ false)

  // ---- epilogue: bias + relu + store. C/D map: col=lane&15, row=(lane>>4)*4+reg
  const int ccol = lane & 15;
  const int crow = (lane >> 4) * 4;
  float bv[4];
#pragma unroll
  for (int nj = 0; nj < 4; ++nj)
    bv[nj] = bias[n0 + wc * 64 + nj * 16 + ccol];

#pragma unroll
  for (int mi = 0; mi < 4; ++mi) {
    const int mrow = m0 + wr * 64 + mi * 16 + crow;
#pragma unroll
    for (int nj = 0; nj < 4; ++nj) {
      const int ocol = n0 + wc * 64 + nj * 16 + ccol;
#pragma unroll
      for (int j = 0; j < 4; ++j) {
        float v = acc[mi][nj][j] + bv[nj];
        v = v > 0.f ? v : 0.f;
        out[(size_t)(mrow + j) * COUT + ocol] = v;
      }
    }
  }
}

extern "C" void kernel_launch(void* const* d_in, const int* in_sizes, int n_in,
                              void* d_out, int out_size, void* d_ws, size_t ws_size,
                              hipStream_t stream) {
  const float* x      = (const float*)d_in[0];   // [64,1000,512] fp32
  const float* kernel = (const float*)d_in[1];   // [512,512,5]   fp32
  const float* bias   = (const float*)d_in[2];   // [512]         fp32
  float* out          = (float*)d_out;           // [64,996,512]  fp32

  __bf16* xb  = (__bf16*)d_ws;                               // 65,536,000 B
  __bf16* wt2 = (__bf16*)((char*)d_ws + (size_t)NX * 2);     // 2,621,440 B

  const int ncv = NX / 8 + NW;                   // 5,406,720 threads
  cvt_kernel<<<(ncv + 255) / 256, 256, 0, stream>>>(x, xb, kernel, wt2);
  tdnn_gemm_kernel<<<NWG, 256, 0, stream>>>(xb, wt2, bias, out);
}